// Round 1
// 385.993 us; speedup vs baseline: 1.0767x; 1.0767x over previous
//
#include <hip/hip_runtime.h>
#include <stdint.h>

// Problem shape (fixed by reference): x[4,2048,4096] f32, CB[4096,4096] i8, SCB[4096] f32
static constexpr int Mtot = 8192;   // B*S
static constexpr int Ntot = 4096;   // OUT
static constexpr int Ktot = 4096;   // IN

using i32x4 = __attribute__((ext_vector_type(4))) int;

#define GLD16(gptr, lptr)                                                                   \
  __builtin_amdgcn_global_load_lds((const __attribute__((address_space(1))) void*)(gptr),   \
                                   (__attribute__((address_space(3))) void*)(lptr), 16, 0, 0)

// ---------------------------------------------------------------------------
// Kernel 1 (fused prep):
//  blocks [0, 16384)      : repack CB int32 -> int8
//  blocks [16384, 24576)  : row-wise dynamic int8 quant of x (one block/row)
// ---------------------------------------------------------------------------
__global__ __launch_bounds__(256) void prep_kernel(const int* __restrict__ cb32,
                                                   int8_t* __restrict__ cb8,
                                                   const float* __restrict__ x,
                                                   int8_t* __restrict__ xq,
                                                   float* __restrict__ sx) {
  __shared__ float wmax[4];
  if (blockIdx.x < 16384) {
    const int idx = blockIdx.x * 256 + threadIdx.x;  // one int4 -> one packed int
    const int4 v = reinterpret_cast<const int4*>(cb32)[idx];
    const unsigned packed = (unsigned)(v.x & 0xff) | ((unsigned)(v.y & 0xff) << 8) |
                            ((unsigned)(v.z & 0xff) << 16) | ((unsigned)(v.w & 0xff) << 24);
    reinterpret_cast<unsigned*>(cb8)[idx] = packed;
    return;
  }
  const int row = blockIdx.x - 16384;
  const float4* xr = reinterpret_cast<const float4*>(x + (size_t)row * Ktot);
  float4 v[4];
  float am = 0.f;
#pragma unroll
  for (int i = 0; i < 4; ++i) {
    v[i] = xr[threadIdx.x + i * 256];
    am = fmaxf(am, fmaxf(fmaxf(fabsf(v[i].x), fabsf(v[i].y)),
                         fmaxf(fabsf(v[i].z), fabsf(v[i].w))));
  }
#pragma unroll
  for (int off = 32; off > 0; off >>= 1) am = fmaxf(am, __shfl_xor(am, off));
  if ((threadIdx.x & 63) == 0) wmax[threadIdx.x >> 6] = am;
  __syncthreads();
  am = fmaxf(fmaxf(wmax[0], wmax[1]), fmaxf(wmax[2], wmax[3]));
  const float inv = 127.0f / am;
  if (threadIdx.x == 0) sx[row] = am * (1.0f / 127.0f);
  unsigned* dq = reinterpret_cast<unsigned*>(xq + (size_t)row * Ktot);
#pragma unroll
  for (int i = 0; i < 4; ++i) {
    const int q0 = (int)rintf(v[i].x * inv);
    const int q1 = (int)rintf(v[i].y * inv);
    const int q2 = (int)rintf(v[i].z * inv);
    const int q3 = (int)rintf(v[i].w * inv);
    dq[threadIdx.x + i * 256] = (unsigned)(q0 & 0xff) | ((unsigned)(q1 & 0xff) << 8) |
                                ((unsigned)(q2 & 0xff) << 16) | ((unsigned)(q3 & 0xff) << 24);
  }
}

// ---------------------------------------------------------------------------
// Kernel 2: int8 GEMM, 256x256 tile, 8-phase-style schedule (T1+T2+T3lite+T5).
//   A = xq [M,K] K-contig, B = CB [N,K] K-contig.
//   BK=128 bytes, 512 threads = 8 waves (2M x 4N), per-wave 128x64 output.
//   LDS 128 KiB: A[2][256][128] @0, B[2][256][128] @65536 (double-buffered).
//   T2 swizzle: LDS[r][c] holds global[r][c ^ ((r&7)<<4)] — staged via linear
//   global_load_lds dest + inverse-swizzled GLOBAL source column (rule 21);
//   ds_read applies the same XOR (folds to per-lane constant (lane&7)<<4).
//   Per K-tile: 4 phases {m0-3 k0, m4-7 k0, m0-3 k1, m4-7 k1}, raw s_barrier
//   pairs + setprio(1) around each 16-MFMA cluster; all 8 staging loads for
//   tile t+1 issued at phase 0 of tile t; single vmcnt drain (__syncthreads)
//   per K-tile after ~4 phases of compute cover.
// ---------------------------------------------------------------------------
__global__ __launch_bounds__(512, 2) void gemm_i8_kernel(const int8_t* __restrict__ A,
                                                         const int8_t* __restrict__ B,
                                                         const float* __restrict__ sx,
                                                         const float* __restrict__ scb,
                                                         float* __restrict__ C) {
  constexpr int BK = 128;
  constexpr int NT = Ktot / BK;  // 32 K-tiles
  __shared__ __align__(16) int8_t lds[131072];

  const int tid = threadIdx.x;
  const int lane = tid & 63;
  const int wid = tid >> 6;

  // T1: XCD-aware swizzle. 512 WGs, 8 XCDs -> each XCD gets 64 consecutive
  // wgids = 4 full m-panel rows (4 MB of A, L2-resident).
  const int wg = (int)blockIdx.x;
  const int wgs = (wg & 7) * 64 + (wg >> 3);
  const int m0 = (wgs >> 4) * 256;  // 32 m-tiles
  const int n0 = (wgs & 15) * 256;  // 16 n-tiles

  const int wm = (wid >> 2) * 128;  // wave M offset: 0 / 128
  const int wn = (wid & 3) * 64;    // wave N offset: 0/64/128/192

  // Staging: 4 loads each for A,B per K-tile; load i covers rows i*64 + tid/8,
  // 16B at column (tid%8)*16. Global column is inverse-swizzled so that the
  // linear LDS write produces the swizzled layout.
  const int srow = tid >> 3;
  const int scol = ((tid & 7) * 16) ^ ((srow & 7) << 4);
  const int8_t* gA = A + (size_t)(m0 + srow) * Ktot + scol;
  const int8_t* gB = B + (size_t)(n0 + srow) * Ktot + scol;

  // Swizzled ds_read offsets. row = w? + f*16 + (lane&15)  =>  row&7 == lane&7.
  const int l15 = lane & 15;
  const int lc0 = ((lane >> 4) * 16) ^ ((lane & 7) << 4);
  const int aOff = (wm + l15) * 128 + lc0;          // + f*2048 ; ^64 for k-half 1
  const int bOff = 65536 + (wn + l15) * 128 + lc0;  // + g*2048 ; ^64 for k-half 1

  i32x4 acc[8][4];
#pragma unroll
  for (int f = 0; f < 8; ++f)
#pragma unroll
    for (int g = 0; g < 4; ++g) acc[f][g] = (i32x4)0;

  // Prologue: stage K-tile 0 into buffer 0, drain.
#pragma unroll
  for (int i = 0; i < 4; ++i) {
    GLD16(gA + (size_t)(i * 64) * Ktot, &lds[i * 8192 + tid * 16]);
    GLD16(gB + (size_t)(i * 64) * Ktot, &lds[65536 + i * 8192 + tid * 16]);
  }
  __syncthreads();

#pragma unroll 2
  for (int t = 0; t < NT; ++t) {
    const int bo = (t & 1) * 32768;        // compute buffer offset
    const int so = ((t & 1) ^ 1) * 32768;  // staging buffer offset
    i32x4 a[4], b[4];

    // ---- P0: k-half 0, m-frags 0-3; issue all staging for tile t+1 ----
#pragma unroll
    for (int f = 0; f < 4; ++f) a[f] = *(const i32x4*)&lds[bo + aOff + f * 2048];
#pragma unroll
    for (int g = 0; g < 4; ++g) b[g] = *(const i32x4*)&lds[bo + bOff + g * 2048];
    if (t + 1 < NT) {
      const size_t kn = (size_t)(t + 1) * BK;
#pragma unroll
      for (int i = 0; i < 4; ++i) {
        GLD16(gA + kn + (size_t)(i * 64) * Ktot, &lds[so + i * 8192 + tid * 16]);
        GLD16(gB + kn + (size_t)(i * 64) * Ktot, &lds[65536 + so + i * 8192 + tid * 16]);
      }
    }
    __builtin_amdgcn_s_barrier();
    __builtin_amdgcn_s_setprio(1);
#pragma unroll
    for (int f = 0; f < 4; ++f)
#pragma unroll
      for (int g = 0; g < 4; ++g)
        acc[f][g] = __builtin_amdgcn_mfma_i32_16x16x64_i8(a[f], b[g], acc[f][g], 0, 0, 0);
    __builtin_amdgcn_s_setprio(0);
    __builtin_amdgcn_s_barrier();

    // ---- P1: k-half 0, m-frags 4-7 (reuse b) ----
#pragma unroll
    for (int f = 0; f < 4; ++f) a[f] = *(const i32x4*)&lds[bo + aOff + (f + 4) * 2048];
    __builtin_amdgcn_s_barrier();
    __builtin_amdgcn_s_setprio(1);
#pragma unroll
    for (int f = 0; f < 4; ++f)
#pragma unroll
      for (int g = 0; g < 4; ++g)
        acc[f + 4][g] = __builtin_amdgcn_mfma_i32_16x16x64_i8(a[f], b[g], acc[f + 4][g], 0, 0, 0);
    __builtin_amdgcn_s_setprio(0);
    __builtin_amdgcn_s_barrier();

    // ---- P2: k-half 1, m-frags 0-3 ----
#pragma unroll
    for (int f = 0; f < 4; ++f) a[f] = *(const i32x4*)&lds[bo + (aOff ^ 64) + f * 2048];
#pragma unroll
    for (int g = 0; g < 4; ++g) b[g] = *(const i32x4*)&lds[bo + (bOff ^ 64) + g * 2048];
    __builtin_amdgcn_s_barrier();
    __builtin_amdgcn_s_setprio(1);
#pragma unroll
    for (int f = 0; f < 4; ++f)
#pragma unroll
      for (int g = 0; g < 4; ++g)
        acc[f][g] = __builtin_amdgcn_mfma_i32_16x16x64_i8(a[f], b[g], acc[f][g], 0, 0, 0);
    __builtin_amdgcn_s_setprio(0);
    __builtin_amdgcn_s_barrier();

    // ---- P3: k-half 1, m-frags 4-7; boundary drain (staging for t+1 has had
    //          ~4 phases of MFMA cover) ----
#pragma unroll
    for (int f = 0; f < 4; ++f) a[f] = *(const i32x4*)&lds[bo + (aOff ^ 64) + (f + 4) * 2048];
    __builtin_amdgcn_s_barrier();
    __builtin_amdgcn_s_setprio(1);
#pragma unroll
    for (int f = 0; f < 4; ++f)
#pragma unroll
      for (int g = 0; g < 4; ++g)
        acc[f + 4][g] = __builtin_amdgcn_mfma_i32_16x16x64_i8(a[f], b[g], acc[f + 4][g], 0, 0, 0);
    __builtin_amdgcn_s_setprio(0);
    __syncthreads();  // vmcnt(0)+lgkmcnt(0)+barrier: tile t+1 fully staged
  }

  // Epilogue: C/D layout col=lane&15, row=(lane>>4)*4+reg (HW-verified,
  // dtype-independent). y = acc * sx[m] * (SCB[n]/127).
  const int col = lane & 15;
  const int rbase = (lane >> 4) * 4;
#pragma unroll
  for (int f = 0; f < 8; ++f) {
    const int gmb = m0 + wm + f * 16 + rbase;
    float sm[4];
#pragma unroll
    for (int r = 0; r < 4; ++r) sm[r] = sx[gmb + r];
#pragma unroll
    for (int g = 0; g < 4; ++g) {
      const int gn = n0 + wn + g * 16 + col;
      const float snv = scb[gn] * (1.0f / 127.0f);
#pragma unroll
      for (int r = 0; r < 4; ++r)
        C[(size_t)(gmb + r) * Ntot + gn] = (float)acc[f][g][r] * sm[r] * snv;
    }
  }
}

// ---------------------------------------------------------------------------
extern "C" void kernel_launch(void* const* d_in, const int* in_sizes, int n_in,
                              void* d_out, int out_size, void* d_ws, size_t ws_size,
                              hipStream_t stream) {
  const float* x = (const float*)d_in[0];
  const int* CB32 = (const int*)d_in[1];  // harness: integer inputs -> const int*
  const float* SCB = (const float*)d_in[2];
  float* out = (float*)d_out;

  // ws layout: xq (32 MB) | cb8 (16 MB) | sx (32 KB)  => needs ~48.03 MB
  int8_t* xq = (int8_t*)d_ws;
  int8_t* cb8 = (int8_t*)d_ws + (size_t)Mtot * Ktot;
  float* sx = (float*)((int8_t*)d_ws + (size_t)Mtot * Ktot + (size_t)Ntot * Ktot);

  // fused prep: 16384 pack blocks + 8192 quant blocks
  prep_kernel<<<16384 + Mtot, 256, 0, stream>>>(CB32, cb8, x, xq, sx);
  // 256x256 tiles: (8192/256) * (4096/256) = 32*16 = 512 WGs (flattened, XCD-swizzled)
  gemm_i8_kernel<<<512, 512, 0, stream>>>(xq, cb8, sx, SCB, out);
}

// Round 2
// 385.313 us; speedup vs baseline: 1.0786x; 1.0018x over previous
//
#include <hip/hip_runtime.h>
#include <stdint.h>

// Problem shape (fixed by reference): x[4,2048,4096] f32, CB[4096,4096] i8, SCB[4096] f32
static constexpr int Mtot = 8192;   // B*S
static constexpr int Ntot = 4096;   // OUT
static constexpr int Ktot = 4096;   // IN

using i32x4 = __attribute__((ext_vector_type(4))) int;

#define GLD16(gptr, lptr)                                                                   \
  __builtin_amdgcn_global_load_lds((const __attribute__((address_space(1))) void*)(gptr),   \
                                   (__attribute__((address_space(3))) void*)(lptr), 16, 0, 0)
#define WAITVM(N) asm volatile("s_waitcnt vmcnt(" #N ")" ::: "memory")

// ---------------------------------------------------------------------------
// Kernel 1 (fused prep):
//  blocks [0, 16384)      : repack CB int32 -> int8
//  blocks [16384, 24576)  : row-wise dynamic int8 quant of x (one block/row)
// ---------------------------------------------------------------------------
__global__ __launch_bounds__(256) void prep_kernel(const int* __restrict__ cb32,
                                                   int8_t* __restrict__ cb8,
                                                   const float* __restrict__ x,
                                                   int8_t* __restrict__ xq,
                                                   float* __restrict__ sx) {
  __shared__ float wmax[4];
  if (blockIdx.x < 16384) {
    const int idx = blockIdx.x * 256 + threadIdx.x;  // one int4 -> one packed int
    const int4 v = reinterpret_cast<const int4*>(cb32)[idx];
    const unsigned packed = (unsigned)(v.x & 0xff) | ((unsigned)(v.y & 0xff) << 8) |
                            ((unsigned)(v.z & 0xff) << 16) | ((unsigned)(v.w & 0xff) << 24);
    reinterpret_cast<unsigned*>(cb8)[idx] = packed;
    return;
  }
  const int row = blockIdx.x - 16384;
  const float4* xr = reinterpret_cast<const float4*>(x + (size_t)row * Ktot);
  float4 v[4];
  float am = 0.f;
#pragma unroll
  for (int i = 0; i < 4; ++i) {
    v[i] = xr[threadIdx.x + i * 256];
    am = fmaxf(am, fmaxf(fmaxf(fabsf(v[i].x), fabsf(v[i].y)),
                         fmaxf(fabsf(v[i].z), fabsf(v[i].w))));
  }
#pragma unroll
  for (int off = 32; off > 0; off >>= 1) am = fmaxf(am, __shfl_xor(am, off));
  if ((threadIdx.x & 63) == 0) wmax[threadIdx.x >> 6] = am;
  __syncthreads();
  am = fmaxf(fmaxf(wmax[0], wmax[1]), fmaxf(wmax[2], wmax[3]));
  const float inv = 127.0f / am;
  if (threadIdx.x == 0) sx[row] = am * (1.0f / 127.0f);
  unsigned* dq = reinterpret_cast<unsigned*>(xq + (size_t)row * Ktot);
#pragma unroll
  for (int i = 0; i < 4; ++i) {
    const int q0 = (int)rintf(v[i].x * inv);
    const int q1 = (int)rintf(v[i].y * inv);
    const int q2 = (int)rintf(v[i].z * inv);
    const int q3 = (int)rintf(v[i].w * inv);
    dq[threadIdx.x + i * 256] = (unsigned)(q0 & 0xff) | ((unsigned)(q1 & 0xff) << 8) |
                                ((unsigned)(q2 & 0xff) << 16) | ((unsigned)(q3 & 0xff) << 24);
  }
}

// ---------------------------------------------------------------------------
// Kernel 2: int8 GEMM, 256x256 tile, 8-phase schedule with COUNTED vmcnt (T4).
//   A = xq [M,K] K-contig, B = CB [N,K] K-contig.
//   BK=128 bytes, 512 threads = 8 waves (2M x 4N), per-wave 128x64 output.
//   LDS 128 KiB: A[2][256][128] @0, B[2][256][128] @65536 (double-buffered).
//   T2 swizzle (verified r1: bank conflicts -> 0): linear G-load-lds dest +
//   inverse-swizzled GLOBAL source column + XOR'd ds_read address.
//   T4 wait derivation (per-tile load order: B0-3 @P0, A0,A2,A1,A3 @P2):
//     end-P3:  vmcnt(2) -> B(t+1)+A0,A2(t+1) landed; A1,A3 in flight
//     post-P0: vmcnt(4) -> A1,A3(t) landed; B(t+2) in flight
//   Every wave issues the identical sequence, so own-vmcnt<=N + s_barrier
//   guarantees ALL waves' oldest loads are in LDS. vmcnt never drains to 0
//   in the main loop; last tile is peeled (its P0 wait must be vmcnt(0)).
// ---------------------------------------------------------------------------
__global__ __launch_bounds__(512, 2) void gemm_i8_kernel(const int8_t* __restrict__ A,
                                                         const int8_t* __restrict__ B,
                                                         const float* __restrict__ sx,
                                                         const float* __restrict__ scb,
                                                         float* __restrict__ C) {
  constexpr int BK = 128;
  constexpr int NT = Ktot / BK;  // 32 K-tiles
  __shared__ __align__(16) int8_t lds[131072];

  const int tid = threadIdx.x;
  const int lane = tid & 63;
  const int wid = tid >> 6;

  // T1: XCD-aware swizzle. 512 WGs, 8 XCDs -> each XCD gets 64 consecutive
  // wgids = 4 full m-panel rows (4 MB of A, L2-resident).
  const int wg = (int)blockIdx.x;
  const int wgs = (wg & 7) * 64 + (wg >> 3);
  const int m0 = (wgs >> 4) * 256;  // 32 m-tiles
  const int n0 = (wgs & 15) * 256;  // 16 n-tiles

  const int wm = (wid >> 2) * 128;  // wave M offset: 0 / 128
  const int wn = (wid & 3) * 64;    // wave N offset: 0/64/128/192

  // Staging: load i covers rows i*64 + tid/8, 16B at column (tid%8)*16,
  // global column inverse-swizzled so the linear LDS write lands swizzled.
  const int srow = tid >> 3;
  const int scol = ((tid & 7) * 16) ^ ((srow & 7) << 4);
  const int8_t* gA = A + (size_t)(m0 + srow) * Ktot + scol;
  const int8_t* gB = B + (size_t)(n0 + srow) * Ktot + scol;

  // Swizzled ds_read offsets. row = w? + f*16 + (lane&15)  =>  row&7 == lane&7.
  const int l15 = lane & 15;
  const int lc0 = ((lane >> 4) * 16) ^ ((lane & 7) << 4);
  const int aOff = (wm + l15) * 128 + lc0;          // + f*2048 ; ^64 for k-half 1
  const int bOff = 65536 + (wn + l15) * 128 + lc0;  // + g*2048 ; ^64 for k-half 1

  i32x4 acc[8][4];
#pragma unroll
  for (int f = 0; f < 8; ++f)
#pragma unroll
    for (int g = 0; g < 4; ++g) acc[f][g] = (i32x4)0;

  // Prologue: stage K-tile 0 into buffer 0, order B0-3, A0, A2, A1, A3.
#pragma unroll
  for (int i = 0; i < 4; ++i) GLD16(gB + (size_t)(i * 64) * Ktot, &lds[65536 + i * 8192 + tid * 16]);
  GLD16(gA + (size_t)(0 * 64) * Ktot, &lds[0 * 8192 + tid * 16]);
  GLD16(gA + (size_t)(2 * 64) * Ktot, &lds[2 * 8192 + tid * 16]);
  GLD16(gA + (size_t)(1 * 64) * Ktot, &lds[1 * 8192 + tid * 16]);
  GLD16(gA + (size_t)(3 * 64) * Ktot, &lds[3 * 8192 + tid * 16]);
  WAITVM(2);  // B + A0,A2 landed; A1,A3 in flight (loop-entry invariant)
  __builtin_amdgcn_s_barrier();

  for (int t = 0; t < NT - 1; ++t) {
    const int bo = (t & 1) * 32768;  // compute buffer offset
    const int so = bo ^ 32768;       // staging buffer offset
    const size_t kn = (size_t)(t + 1) * BK;
    i32x4 a[4], b[4];

    // ---- P0: k-half 0, m-frags 0-3; issue B-loads for t+1 ----
#pragma unroll
    for (int f = 0; f < 4; ++f) a[f] = *(const i32x4*)&lds[bo + aOff + f * 2048];
#pragma unroll
    for (int g = 0; g < 4; ++g) b[g] = *(const i32x4*)&lds[bo + bOff + g * 2048];
#pragma unroll
    for (int i = 0; i < 4; ++i)
      GLD16(gB + kn + (size_t)(i * 64) * Ktot, &lds[65536 + so + i * 8192 + tid * 16]);
    __builtin_amdgcn_s_barrier();
    __builtin_amdgcn_s_setprio(1);
#pragma unroll
    for (int f = 0; f < 4; ++f)
#pragma unroll
      for (int g = 0; g < 4; ++g)
        acc[f][g] = __builtin_amdgcn_mfma_i32_16x16x64_i8(a[f], b[g], acc[f][g], 0, 0, 0);
    __builtin_amdgcn_s_setprio(0);
    WAITVM(4);  // A1,A3(t) landed; B(t+1) in flight
    __builtin_amdgcn_s_barrier();

    // ---- P1: k-half 0, m-frags 4-7 (reuse b) ----
#pragma unroll
    for (int f = 0; f < 4; ++f) a[f] = *(const i32x4*)&lds[bo + aOff + (f + 4) * 2048];
    __builtin_amdgcn_s_barrier();
    __builtin_amdgcn_s_setprio(1);
#pragma unroll
    for (int f = 0; f < 4; ++f)
#pragma unroll
      for (int g = 0; g < 4; ++g)
        acc[f + 4][g] = __builtin_amdgcn_mfma_i32_16x16x64_i8(a[f], b[g], acc[f + 4][g], 0, 0, 0);
    __builtin_amdgcn_s_setprio(0);
    __builtin_amdgcn_s_barrier();

    // ---- P2: k-half 1, m-frags 0-3; issue A-loads for t+1 (A0,A2,A1,A3) ----
#pragma unroll
    for (int f = 0; f < 4; ++f) a[f] = *(const i32x4*)&lds[bo + (aOff ^ 64) + f * 2048];
#pragma unroll
    for (int g = 0; g < 4; ++g) b[g] = *(const i32x4*)&lds[bo + (bOff ^ 64) + g * 2048];
    GLD16(gA + kn + (size_t)(0 * 64) * Ktot, &lds[so + 0 * 8192 + tid * 16]);
    GLD16(gA + kn + (size_t)(2 * 64) * Ktot, &lds[so + 2 * 8192 + tid * 16]);
    GLD16(gA + kn + (size_t)(1 * 64) * Ktot, &lds[so + 1 * 8192 + tid * 16]);
    GLD16(gA + kn + (size_t)(3 * 64) * Ktot, &lds[so + 3 * 8192 + tid * 16]);
    __builtin_amdgcn_s_barrier();
    __builtin_amdgcn_s_setprio(1);
#pragma unroll
    for (int f = 0; f < 4; ++f)
#pragma unroll
      for (int g = 0; g < 4; ++g)
        acc[f][g] = __builtin_amdgcn_mfma_i32_16x16x64_i8(a[f], b[g], acc[f][g], 0, 0, 0);
    __builtin_amdgcn_s_setprio(0);
    __builtin_amdgcn_s_barrier();

    // ---- P3: k-half 1, m-frags 4-7; counted boundary wait ----
#pragma unroll
    for (int f = 0; f < 4; ++f) a[f] = *(const i32x4*)&lds[bo + (aOff ^ 64) + (f + 4) * 2048];
    __builtin_amdgcn_s_barrier();
    __builtin_amdgcn_s_setprio(1);
#pragma unroll
    for (int f = 0; f < 4; ++f)
#pragma unroll
      for (int g = 0; g < 4; ++g)
        acc[f + 4][g] = __builtin_amdgcn_mfma_i32_16x16x64_i8(a[f], b[g], acc[f + 4][g], 0, 0, 0);
    __builtin_amdgcn_s_setprio(0);
    WAITVM(2);  // B(t+1) + A0,A2(t+1) landed; A1,A3(t+1) in flight
    __builtin_amdgcn_s_barrier();
  }

  // ---- Peeled last tile (t = NT-1): no staging; P0 wait must drain to 0 ----
  {
    const int bo = ((NT - 1) & 1) * 32768;
    i32x4 a[4], b[4];
#pragma unroll
    for (int f = 0; f < 4; ++f) a[f] = *(const i32x4*)&lds[bo + aOff + f * 2048];
#pragma unroll
    for (int g = 0; g < 4; ++g) b[g] = *(const i32x4*)&lds[bo + bOff + g * 2048];
    __builtin_amdgcn_s_barrier();
    __builtin_amdgcn_s_setprio(1);
#pragma unroll
    for (int f = 0; f < 4; ++f)
#pragma unroll
      for (int g = 0; g < 4; ++g)
        acc[f][g] = __builtin_amdgcn_mfma_i32_16x16x64_i8(a[f], b[g], acc[f][g], 0, 0, 0);
    __builtin_amdgcn_s_setprio(0);
    WAITVM(0);  // no new loads issued this tile: must fully drain for A1,A3
    __builtin_amdgcn_s_barrier();

#pragma unroll
    for (int f = 0; f < 4; ++f) a[f] = *(const i32x4*)&lds[bo + aOff + (f + 4) * 2048];
    __builtin_amdgcn_s_barrier();
    __builtin_amdgcn_s_setprio(1);
#pragma unroll
    for (int f = 0; f < 4; ++f)
#pragma unroll
      for (int g = 0; g < 4; ++g)
        acc[f + 4][g] = __builtin_amdgcn_mfma_i32_16x16x64_i8(a[f], b[g], acc[f + 4][g], 0, 0, 0);
    __builtin_amdgcn_s_setprio(0);
    __builtin_amdgcn_s_barrier();

#pragma unroll
    for (int f = 0; f < 4; ++f) a[f] = *(const i32x4*)&lds[bo + (aOff ^ 64) + f * 2048];
#pragma unroll
    for (int g = 0; g < 4; ++g) b[g] = *(const i32x4*)&lds[bo + (bOff ^ 64) + g * 2048];
    __builtin_amdgcn_s_barrier();
    __builtin_amdgcn_s_setprio(1);
#pragma unroll
    for (int f = 0; f < 4; ++f)
#pragma unroll
      for (int g = 0; g < 4; ++g)
        acc[f][g] = __builtin_amdgcn_mfma_i32_16x16x64_i8(a[f], b[g], acc[f][g], 0, 0, 0);
    __builtin_amdgcn_s_setprio(0);
    __builtin_amdgcn_s_barrier();

#pragma unroll
    for (int f = 0; f < 4; ++f) a[f] = *(const i32x4*)&lds[bo + (aOff ^ 64) + (f + 4) * 2048];
    __builtin_amdgcn_s_setprio(1);
#pragma unroll
    for (int f = 0; f < 4; ++f)
#pragma unroll
      for (int g = 0; g < 4; ++g)
        acc[f + 4][g] = __builtin_amdgcn_mfma_i32_16x16x64_i8(a[f], b[g], acc[f + 4][g], 0, 0, 0);
    __builtin_amdgcn_s_setprio(0);
  }

  // Epilogue: C/D layout col=lane&15, row=(lane>>4)*4+reg (HW-verified,
  // dtype-independent). y = acc * sx[m] * (SCB[n]/127).
  const int col = lane & 15;
  const int rbase = (lane >> 4) * 4;
#pragma unroll
  for (int f = 0; f < 8; ++f) {
    const int gmb = m0 + wm + f * 16 + rbase;
    float sm[4];
#pragma unroll
    for (int r = 0; r < 4; ++r) sm[r] = sx[gmb + r];
#pragma unroll
    for (int g = 0; g < 4; ++g) {
      const int gn = n0 + wn + g * 16 + col;
      const float snv = scb[gn] * (1.0f / 127.0f);
#pragma unroll
      for (int r = 0; r < 4; ++r)
        C[(size_t)(gmb + r) * Ntot + gn] = (float)acc[f][g][r] * sm[r] * snv;
    }
  }
}

// ---------------------------------------------------------------------------
extern "C" void kernel_launch(void* const* d_in, const int* in_sizes, int n_in,
                              void* d_out, int out_size, void* d_ws, size_t ws_size,
                              hipStream_t stream) {
  const float* x = (const float*)d_in[0];
  const int* CB32 = (const int*)d_in[1];  // harness: integer inputs -> const int*
  const float* SCB = (const float*)d_in[2];
  float* out = (float*)d_out;

  // ws layout: xq (32 MB) | cb8 (16 MB) | sx (32 KB)  => needs ~48.03 MB
  int8_t* xq = (int8_t*)d_ws;
  int8_t* cb8 = (int8_t*)d_ws + (size_t)Mtot * Ktot;
  float* sx = (float*)((int8_t*)d_ws + (size_t)Mtot * Ktot + (size_t)Ntot * Ktot);

  // fused prep: 16384 pack blocks + 8192 quant blocks
  prep_kernel<<<16384 + Mtot, 256, 0, stream>>>(CB32, cb8, x, xq, sx);
  // 256x256 tiles: (8192/256) * (4096/256) = 32*16 = 512 WGs (flattened, XCD-swizzled)
  gemm_i8_kernel<<<512, 512, 0, stream>>>(xq, cb8, sx, SCB, out);
}

// Round 3
// 375.970 us; speedup vs baseline: 1.1054x; 1.0248x over previous
//
#include <hip/hip_runtime.h>
#include <stdint.h>

// Problem shape (fixed by reference): x[4,2048,4096] f32, CB[4096,4096] i8, SCB[4096] f32
static constexpr int Mtot = 8192;   // B*S
static constexpr int Ntot = 4096;   // OUT
static constexpr int Ktot = 4096;   // IN

using i32x4 = __attribute__((ext_vector_type(4))) int;

#define GLD16(gptr, lptr)                                                                   \
  __builtin_amdgcn_global_load_lds((const __attribute__((address_space(1))) void*)(gptr),   \
                                   (__attribute__((address_space(3))) void*)(lptr), 16, 0, 0)
#define WAITVM(N) asm volatile("s_waitcnt vmcnt(" #N ")" ::: "memory")

// ---------------------------------------------------------------------------
// Kernel 1 (fused prep):
//  blocks [0, 16384)      : repack CB int32 -> int8
//  blocks [16384, 24576)  : row-wise dynamic int8 quant of x (one block/row)
// ---------------------------------------------------------------------------
__global__ __launch_bounds__(256) void prep_kernel(const int* __restrict__ cb32,
                                                   int8_t* __restrict__ cb8,
                                                   const float* __restrict__ x,
                                                   int8_t* __restrict__ xq,
                                                   float* __restrict__ sx) {
  __shared__ float wmax[4];
  if (blockIdx.x < 16384) {
    const int idx = blockIdx.x * 256 + threadIdx.x;  // one int4 -> one packed int
    const int4 v = reinterpret_cast<const int4*>(cb32)[idx];
    const unsigned packed = (unsigned)(v.x & 0xff) | ((unsigned)(v.y & 0xff) << 8) |
                            ((unsigned)(v.z & 0xff) << 16) | ((unsigned)(v.w & 0xff) << 24);
    reinterpret_cast<unsigned*>(cb8)[idx] = packed;
    return;
  }
  const int row = blockIdx.x - 16384;
  const float4* xr = reinterpret_cast<const float4*>(x + (size_t)row * Ktot);
  float4 v[4];
  float am = 0.f;
#pragma unroll
  for (int i = 0; i < 4; ++i) {
    v[i] = xr[threadIdx.x + i * 256];
    am = fmaxf(am, fmaxf(fmaxf(fabsf(v[i].x), fabsf(v[i].y)),
                         fmaxf(fabsf(v[i].z), fabsf(v[i].w))));
  }
#pragma unroll
  for (int off = 32; off > 0; off >>= 1) am = fmaxf(am, __shfl_xor(am, off));
  if ((threadIdx.x & 63) == 0) wmax[threadIdx.x >> 6] = am;
  __syncthreads();
  am = fmaxf(fmaxf(wmax[0], wmax[1]), fmaxf(wmax[2], wmax[3]));
  const float inv = 127.0f / am;
  if (threadIdx.x == 0) sx[row] = am * (1.0f / 127.0f);
  unsigned* dq = reinterpret_cast<unsigned*>(xq + (size_t)row * Ktot);
#pragma unroll
  for (int i = 0; i < 4; ++i) {
    const int q0 = (int)rintf(v[i].x * inv);
    const int q1 = (int)rintf(v[i].y * inv);
    const int q2 = (int)rintf(v[i].z * inv);
    const int q3 = (int)rintf(v[i].w * inv);
    dq[threadIdx.x + i * 256] = (unsigned)(q0 & 0xff) | ((unsigned)(q1 & 0xff) << 8) |
                                ((unsigned)(q2 & 0xff) << 16) | ((unsigned)(q3 & 0xff) << 24);
  }
}

// ---------------------------------------------------------------------------
// Kernel 2: int8 GEMM, 256x256 tile, 4-phase pipelined schedule.
//   T2 swizzle (r1: conflicts->0), T4 counted vmcnt (r2), and NEW (r3):
//   ds_read fragments are issued ONE PHASE AHEAD so every MFMA cluster covers
//   the next phase's LDS latency. Phase->compute map:
//     P0: acc[0..3]  += aE(a0-3,k0) * b0   (frags read at P3 of prev tile)
//     P1: acc[0..3]  += aO(a0-3,k1) * b1   (frags read at P0)
//     P2: acc[4..7]  += aE(a4-7,k0) * b0   (aE re-read at P1)
//     P3: acc[4..7]  += aO(a4-7,k1) * b1   (aO re-read at P2)
//   Read-gating invariants (vmcnt-wait THEN barrier, all waves):
//     - A1/A3 regions of cur readable only after end-P0 WAITVM(4)+barrier.
//     - staging-buffer B/A0/A2 readable only after end-P2 WAITVM(2)+barrier.
//   Staging (into `so`, for tile t+1): B0-3 @P0, A0,A2,A1,A3 @P1.
//   vmcnt: P0 WAITVM(4) [drains A1,A3(cur)], P2 WAITVM(2) [drains B,A0,A2(so)].
//   Never 0 in the main loop; last tile peeled with a full drain.
// ---------------------------------------------------------------------------
__global__ __launch_bounds__(512, 2) void gemm_i8_kernel(const int8_t* __restrict__ A,
                                                         const int8_t* __restrict__ B,
                                                         const float* __restrict__ sx,
                                                         const float* __restrict__ scb,
                                                         float* __restrict__ C) {
  constexpr int BK = 128;
  constexpr int NT = Ktot / BK;  // 32 K-tiles
  __shared__ __align__(16) int8_t lds[131072];

  const int tid = threadIdx.x;
  const int lane = tid & 63;
  const int wid = tid >> 6;

  // T1: XCD-aware swizzle. 512 WGs, 8 XCDs -> each XCD gets 64 consecutive
  // wgids = 4 full m-panel rows.
  const int wg = (int)blockIdx.x;
  const int wgs = (wg & 7) * 64 + (wg >> 3);
  const int m0 = (wgs >> 4) * 256;  // 32 m-tiles
  const int n0 = (wgs & 15) * 256;  // 16 n-tiles

  const int wm = (wid >> 2) * 128;  // wave M offset: 0 / 128
  const int wn = (wid & 3) * 64;    // wave N offset: 0/64/128/192

  // Staging: load i covers rows i*64 + tid/8, 16B at column (tid%8)*16,
  // global column inverse-swizzled so the linear LDS write lands swizzled.
  const int srow = tid >> 3;
  const int scol = ((tid & 7) * 16) ^ ((srow & 7) << 4);
  const int8_t* gA = A + (size_t)(m0 + srow) * Ktot + scol;
  const int8_t* gB = B + (size_t)(n0 + srow) * Ktot + scol;

  // Swizzled ds_read offsets. row = w? + f*16 + (lane&15)  =>  row&7 == lane&7.
  const int l15 = lane & 15;
  const int lc0 = ((lane >> 4) * 16) ^ ((lane & 7) << 4);
  const int aOff = (wm + l15) * 128 + lc0;          // + f*2048 ; ^64 for k-half 1
  const int bOff = 65536 + (wn + l15) * 128 + lc0;  // + g*2048 ; ^64 for k-half 1

  i32x4 acc[8][4];
#pragma unroll
  for (int f = 0; f < 8; ++f)
#pragma unroll
    for (int g = 0; g < 4; ++g) acc[f][g] = (i32x4)0;

  // Fragment double-buffer registers (static indices only, rule 20).
  i32x4 aE[4], aO[4], b0v[4], b1v[4];

  // Prologue: stage K-tile 0 into buffer 0, order B0-3, A0, A2, A1, A3.
#pragma unroll
  for (int i = 0; i < 4; ++i) GLD16(gB + (size_t)(i * 64) * Ktot, &lds[65536 + i * 8192 + tid * 16]);
  GLD16(gA + (size_t)(0 * 64) * Ktot, &lds[0 * 8192 + tid * 16]);
  GLD16(gA + (size_t)(2 * 64) * Ktot, &lds[2 * 8192 + tid * 16]);
  GLD16(gA + (size_t)(1 * 64) * Ktot, &lds[1 * 8192 + tid * 16]);
  GLD16(gA + (size_t)(3 * 64) * Ktot, &lds[3 * 8192 + tid * 16]);
  WAITVM(2);  // B + A0,A2 landed; A1,A3 in flight (loop-entry invariant)
  __builtin_amdgcn_s_barrier();
  // Pre-read P0 frags of tile 0 (regions B / A0 / A2 of buf0 — all confirmed).
#pragma unroll
  for (int f = 0; f < 4; ++f) aE[f] = *(const i32x4*)&lds[aOff + f * 2048];
#pragma unroll
  for (int g = 0; g < 4; ++g) b0v[g] = *(const i32x4*)&lds[bOff + g * 2048];

#pragma unroll 2
  for (int t = 0; t < NT - 1; ++t) {
    const int bo = (t & 1) * 32768;  // compute buffer offset
    const int so = bo ^ 32768;       // staging buffer offset
    const size_t kn = (size_t)(t + 1) * BK;

    // ---- P0: MFMA (a0-3,k0)*b0 ; read P1 frags (cur, un-gated) ; issue B(t+1)
    //      WAITVM(4): A1,A3(cur) landed (B(t+1) stays in flight) ----
#pragma unroll
    for (int i = 0; i < 4; ++i)
      GLD16(gB + kn + (size_t)(i * 64) * Ktot, &lds[65536 + so + i * 8192 + tid * 16]);
    WAITVM(4);
#pragma unroll
    for (int f = 0; f < 4; ++f) aO[f] = *(const i32x4*)&lds[bo + (aOff ^ 64) + f * 2048];
#pragma unroll
    for (int g = 0; g < 4; ++g) b1v[g] = *(const i32x4*)&lds[bo + (bOff ^ 64) + g * 2048];
    __builtin_amdgcn_s_setprio(1);
#pragma unroll
    for (int f = 0; f < 4; ++f)
#pragma unroll
      for (int g = 0; g < 4; ++g)
        acc[f][g] = __builtin_amdgcn_mfma_i32_16x16x64_i8(aE[f], b0v[g], acc[f][g], 0, 0, 0);
    __builtin_amdgcn_s_setprio(0);
    __builtin_amdgcn_s_barrier();

    // ---- P1: MFMA (a0-3,k1)*b1 ; read P2 frags (A1/A3 k0 — gated by end-P0) ;
    //      issue A(t+1) in order A0,A2,A1,A3 ----
    GLD16(gA + kn + (size_t)(0 * 64) * Ktot, &lds[so + 0 * 8192 + tid * 16]);
    GLD16(gA + kn + (size_t)(2 * 64) * Ktot, &lds[so + 2 * 8192 + tid * 16]);
    GLD16(gA + kn + (size_t)(1 * 64) * Ktot, &lds[so + 1 * 8192 + tid * 16]);
    GLD16(gA + kn + (size_t)(3 * 64) * Ktot, &lds[so + 3 * 8192 + tid * 16]);
#pragma unroll
    for (int f = 0; f < 4; ++f) aE[f] = *(const i32x4*)&lds[bo + aOff + (f + 4) * 2048];
    __builtin_amdgcn_s_setprio(1);
#pragma unroll
    for (int f = 0; f < 4; ++f)
#pragma unroll
      for (int g = 0; g < 4; ++g)
        acc[f][g] = __builtin_amdgcn_mfma_i32_16x16x64_i8(aO[f], b1v[g], acc[f][g], 0, 0, 0);
    __builtin_amdgcn_s_setprio(0);
    __builtin_amdgcn_s_barrier();

    // ---- P2: MFMA (a4-7,k0)*b0 ; read P3 frags (A1/A3 k1) ;
    //      WAITVM(2): B,A0,A2(t+1) landed (A1,A3(t+1) stay in flight) ----
#pragma unroll
    for (int f = 0; f < 4; ++f) aO[f] = *(const i32x4*)&lds[bo + (aOff ^ 64) + (f + 4) * 2048];
    __builtin_amdgcn_s_setprio(1);
#pragma unroll
    for (int f = 0; f < 4; ++f)
#pragma unroll
      for (int g = 0; g < 4; ++g)
        acc[f + 4][g] = __builtin_amdgcn_mfma_i32_16x16x64_i8(aE[f], b0v[g], acc[f + 4][g], 0, 0, 0);
    __builtin_amdgcn_s_setprio(0);
    WAITVM(2);
    __builtin_amdgcn_s_barrier();

    // ---- P3: MFMA (a4-7,k1)*b1 ; read NEXT-tile P0 frags from `so`
    //      (regions B/A0/A2 — confirmed by end-P2 wait+barrier) ----
#pragma unroll
    for (int f = 0; f < 4; ++f) aE[f] = *(const i32x4*)&lds[so + aOff + f * 2048];
#pragma unroll
    for (int g = 0; g < 4; ++g) b0v[g] = *(const i32x4*)&lds[so + bOff + g * 2048];
    __builtin_amdgcn_s_setprio(1);
#pragma unroll
    for (int f = 0; f < 4; ++f)
#pragma unroll
      for (int g = 0; g < 4; ++g)
        acc[f + 4][g] = __builtin_amdgcn_mfma_i32_16x16x64_i8(aO[f], b1v[g], acc[f + 4][g], 0, 0, 0);
    __builtin_amdgcn_s_setprio(0);
    __builtin_amdgcn_s_barrier();
  }

  // ---- Peeled last tile (t = NT-1): no staging; entry outstanding = A1,A3(cur).
  {
    const int bo = ((NT - 1) & 1) * 32768;
    // P0: full drain (no new issues -> counted wait can't express A1,A3)
    WAITVM(0);
#pragma unroll
    for (int f = 0; f < 4; ++f) aO[f] = *(const i32x4*)&lds[bo + (aOff ^ 64) + f * 2048];
#pragma unroll
    for (int g = 0; g < 4; ++g) b1v[g] = *(const i32x4*)&lds[bo + (bOff ^ 64) + g * 2048];
    __builtin_amdgcn_s_setprio(1);
#pragma unroll
    for (int f = 0; f < 4; ++f)
#pragma unroll
      for (int g = 0; g < 4; ++g)
        acc[f][g] = __builtin_amdgcn_mfma_i32_16x16x64_i8(aE[f], b0v[g], acc[f][g], 0, 0, 0);
    __builtin_amdgcn_s_setprio(0);
    __builtin_amdgcn_s_barrier();  // gates A1/A3 reads below (all waves drained)
    // P1
#pragma unroll
    for (int f = 0; f < 4; ++f) aE[f] = *(const i32x4*)&lds[bo + aOff + (f + 4) * 2048];
    __builtin_amdgcn_s_setprio(1);
#pragma unroll
    for (int f = 0; f < 4; ++f)
#pragma unroll
      for (int g = 0; g < 4; ++g)
        acc[f][g] = __builtin_amdgcn_mfma_i32_16x16x64_i8(aO[f], b1v[g], acc[f][g], 0, 0, 0);
    __builtin_amdgcn_s_setprio(0);
    // P2
#pragma unroll
    for (int f = 0; f < 4; ++f) aO[f] = *(const i32x4*)&lds[bo + (aOff ^ 64) + (f + 4) * 2048];
    __builtin_amdgcn_s_setprio(1);
#pragma unroll
    for (int f = 0; f < 4; ++f)
#pragma unroll
      for (int g = 0; g < 4; ++g)
        acc[f + 4][g] = __builtin_amdgcn_mfma_i32_16x16x64_i8(aE[f], b0v[g], acc[f + 4][g], 0, 0, 0);
    __builtin_amdgcn_s_setprio(0);
    // P3
    __builtin_amdgcn_s_setprio(1);
#pragma unroll
    for (int f = 0; f < 4; ++f)
#pragma unroll
      for (int g = 0; g < 4; ++g)
        acc[f + 4][g] = __builtin_amdgcn_mfma_i32_16x16x64_i8(aO[f], b1v[g], acc[f + 4][g], 0, 0, 0);
    __builtin_amdgcn_s_setprio(0);
  }

  // Epilogue: C/D layout col=lane&15, row=(lane>>4)*4+reg (HW-verified,
  // dtype-independent). y = acc * sx[m] * (SCB[n]/127).
  const int col = lane & 15;
  const int rbase = (lane >> 4) * 4;
#pragma unroll
  for (int f = 0; f < 8; ++f) {
    const int gmb = m0 + wm + f * 16 + rbase;
    float sm[4];
#pragma unroll
    for (int r = 0; r < 4; ++r) sm[r] = sx[gmb + r];
#pragma unroll
    for (int g = 0; g < 4; ++g) {
      const int gn = n0 + wn + g * 16 + col;
      const float snv = scb[gn] * (1.0f / 127.0f);
#pragma unroll
      for (int r = 0; r < 4; ++r)
        C[(size_t)(gmb + r) * Ntot + gn] = (float)acc[f][g][r] * sm[r] * snv;
    }
  }
}

// ---------------------------------------------------------------------------
extern "C" void kernel_launch(void* const* d_in, const int* in_sizes, int n_in,
                              void* d_out, int out_size, void* d_ws, size_t ws_size,
                              hipStream_t stream) {
  const float* x = (const float*)d_in[0];
  const int* CB32 = (const int*)d_in[1];  // harness: integer inputs -> const int*
  const float* SCB = (const float*)d_in[2];
  float* out = (float*)d_out;

  // ws layout: xq (32 MB) | cb8 (16 MB) | sx (32 KB)  => needs ~48.03 MB
  int8_t* xq = (int8_t*)d_ws;
  int8_t* cb8 = (int8_t*)d_ws + (size_t)Mtot * Ktot;
  float* sx = (float*)((int8_t*)d_ws + (size_t)Mtot * Ktot + (size_t)Ntot * Ktot);

  // fused prep: 16384 pack blocks + 8192 quant blocks
  prep_kernel<<<16384 + Mtot, 256, 0, stream>>>(CB32, cb8, x, xq, sx);
  // 256x256 tiles: (8192/256) * (4096/256) = 32*16 = 512 WGs (flattened, XCD-swizzled)
  gemm_i8_kernel<<<512, 512, 0, stream>>>(xq, cb8, sx, SCB, out);
}